// Round 1
// 840.151 us; speedup vs baseline: 1.0197x; 1.0197x over previous
//
#include <hip/hip_runtime.h>

// Problem constants (fixed by setup_inputs): B=64, nh=1024, nv=2048, fp32.
#define B_  64
#define NH  1024
#define NV  2048
#define HS  64              // h rows handled per block
#define HSPLIT (NH / HS)    // 16 h-slices
#define B2_ELEMS (B_ * NV)  // 131072

// clang ext_vector: supports scalar broadcast ops and nontemporal builtins
// (HIP's float4 is a struct and __builtin_nontemporal_* rejects it).
typedef float v4f __attribute__((ext_vector_type(4)));

// Tiny kernel: seed the b2 region of d_out with b1 (d_out is re-poisoned
// to 0xAA before every timed launch, so this must run every call).
__global__ __launch_bounds__(256) void seed_b2(const float* __restrict__ b1,
                                               float* __restrict__ b2) {
    int i = blockIdx.x * blockDim.x + threadIdx.x;  // float4 index
    ((v4f*)b2)[i] = ((const v4f*)b1)[i];
}

// Fused: wt2 = scale*wt1 (streamed, nontemporal), b2 += sum_h coef*wt1
// (atomic partials, L2-resident since streams bypass with nt hints).
__global__ __launch_bounds__(256) void fused_convert(
    const float* __restrict__ wt1,
    const float* __restrict__ muh1,
    const float* __restrict__ muh2,
    const float* __restrict__ varh1,
    const float* __restrict__ varh2,
    float* __restrict__ b2,   // d_out + 0
    float* __restrict__ wt2)  // d_out + B2_ELEMS
{
    __shared__ float s_scale[HS];
    __shared__ float s_coef[HS];

    const int tid = threadIdx.x;
    const int b   = blockIdx.z;
    const int h0  = blockIdx.y * HS;
    const int v   = blockIdx.x * (256 * 4) + tid * 4;  // float4 column base

    if (tid < HS) {
        const int h = h0 + tid;
        const float sv1 = varh1[b * NH + h];
        const float sv2 = varh2[b * NH + h];
        const float s   = sqrtf(sv1) / sqrtf(sv2);   // match ref exactly
        s_scale[tid] = s;
        s_coef[tid]  = muh1[b * NH + h] - s * muh2[b * NH + h];
    }
    __syncthreads();

    const size_t base = ((size_t)b * NH + h0) * NV + v;
    const v4f* __restrict__ src = (const v4f*)(wt1 + base);
    v4f*       __restrict__ dst = (v4f*)(wt2 + base);
    const int rowstride = NV / 4;  // 512 float4 per h row

    v4f acc = {0.f, 0.f, 0.f, 0.f};

    // Phase-split: 8 nontemporal loads in flight, THEN 8 stores+FMAs.
    // unroll 2 lets the compiler overlap group g+1's loads with group g's
    // stores (~16 outstanding VMEM ops/wave vs ~4 before).
    #pragma unroll 2
    for (int g = 0; g < HS / 8; ++g) {
        v4f w[8];
        #pragma unroll
        for (int j = 0; j < 8; ++j)
            w[j] = __builtin_nontemporal_load(src + (size_t)(g * 8 + j) * rowstride);
        #pragma unroll
        for (int j = 0; j < 8; ++j) {
            const int hh = g * 8 + j;
            const float s = s_scale[hh];
            const float c = s_coef[hh];
            __builtin_nontemporal_store(s * w[j], dst + (size_t)hh * rowstride);
            acc += c * w[j];
        }
    }

    float* out = b2 + (size_t)b * NV + v;
    atomicAdd(out + 0, acc.x);
    atomicAdd(out + 1, acc.y);
    atomicAdd(out + 2, acc.z);
    atomicAdd(out + 3, acc.w);
}

extern "C" void kernel_launch(void* const* d_in, const int* in_sizes, int n_in,
                              void* d_out, int out_size, void* d_ws, size_t ws_size,
                              hipStream_t stream) {
    const float* b1    = (const float*)d_in[0];
    const float* wt1   = (const float*)d_in[1];
    const float* muh1  = (const float*)d_in[2];
    const float* muh2  = (const float*)d_in[3];
    const float* varh1 = (const float*)d_in[4];
    const float* varh2 = (const float*)d_in[5];

    float* b2  = (float*)d_out;              // [B, nv]
    float* wt2 = (float*)d_out + B2_ELEMS;   // [B, nh, nv]

    // Seed b2 = b1 (must precede the atomic accumulation; same stream => ordered).
    seed_b2<<<B2_ELEMS / 4 / 256, 256, 0, stream>>>(b1, b2);

    // 2048 blocks: (v-chunks=2, h-slices=16, batch=64), 256 thr, float4/thread.
    dim3 grid(NV / (256 * 4), HSPLIT, B_);
    fused_convert<<<grid, 256, 0, stream>>>(wt1, muh1, muh2, varh1, varh2, b2, wt2);
}